// Round 9
// baseline (4829.321 us; speedup 1.0000x reference)
//
#include <hip/hip_runtime.h>
#include <math.h>

namespace {

constexpr int   NT_   = 8;
constexpr int   NB_   = 12;
constexpr float TB_   = 5.0f;
constexpr float MINW_ = 0.001f;
constexpr float MINH_ = 0.001f;
constexpr float MIND_ = 0.001f;
constexpr float LOGZ_ = -2.7568155996140185f;  // -0.5*3*log(2*pi)

constexpr int AP_  = 64;        // A-slab row pitch (floats); XOR swizzle balances banks
constexpr int ASZ_ = 64 * AP_;  // per-wave A-slab floats (4096)
constexpr int PPP_ = 41;        // param-slab pitch (odd -> 2-way banks, free)
constexpr int WAVES_ = 4;       // waves per block

// d_ws layout (floats):
//   WT_blk[32][64][64]      k-major dense tiles              (131072)
//   WT_out[8][2][64][40]    k-major head halves, 40-padded   (40960)
constexpr int WT_BLK_ELEMS = 32 * 4096;
constexpr int WT_OUT_ELEMS = 16 * 2560;

__device__ __forceinline__ float softplus_(float v) {
    return fmaxf(v, 0.0f) + log1pf(__expf(-fabsf(v)));
}

// Rational-quadratic spline, params in registers (verified rounds 4-8).
__device__ __forceinline__ void rq_spline_reg(const float (&p)[37], float xr,
                                              float& y_out, float& lad_out) {
    float mw = -1e30f, mh = -1e30f;
#pragma unroll
    for (int q = 0; q < NB_; ++q) { mw = fmaxf(mw, p[q]); mh = fmaxf(mh, p[NB_ + q]); }

    float ew[NB_], eh[NB_];
    float sw = 0.0f, sh = 0.0f;
#pragma unroll
    for (int q = 0; q < NB_; ++q) { ew[q] = __expf(p[q] - mw);        sw += ew[q]; }
#pragma unroll
    for (int q = 0; q < NB_; ++q) { eh[q] = __expf(p[NB_ + q] - mh);  sh += eh[q]; }

    const float iw = (1.0f - MINW_ * (float)NB_) / sw;
    const float ih = (1.0f - MINH_ * (float)NB_) / sh;

    float cw[NB_ + 1], ch[NB_ + 1];
    cw[0] = -TB_; ch[0] = -TB_;
    float rw = 0.0f, rh = 0.0f;
#pragma unroll
    for (int q = 0; q < NB_; ++q) {
        rw += MINW_ + ew[q] * iw;
        rh += MINH_ + eh[q] * ih;
        cw[q + 1] = fmaf(2.0f * TB_, rw, -TB_);
        ch[q + 1] = fmaf(2.0f * TB_, rh, -TB_);
    }
    cw[NB_] = TB_;
    ch[NB_] = TB_;

    const float xc = fminf(fmaxf(xr, -TB_), TB_);

    int bi = 0;
#pragma unroll
    for (int q = 1; q <= NB_ - 1; ++q) bi += (xc >= cw[q]) ? 1 : 0;

    float in_cw = cw[0], cwn = cw[1], in_ch = ch[0], chn = ch[1];
    float udm1 = 0.0f, ud0 = p[24];
#pragma unroll
    for (int q = 1; q < NB_; ++q) {
        const bool s = (bi == q);
        in_cw = s ? cw[q]         : in_cw;
        cwn   = s ? cw[q + 1]     : cwn;
        in_ch = s ? ch[q]         : in_ch;
        chn   = s ? ch[q + 1]     : chn;
        udm1  = s ? p[24 + q - 1] : udm1;
        ud0   = s ? p[24 + q]     : ud0;
    }
    const float in_w = cwn - in_cw;
    const float in_h = chn - in_ch;
    const float d_k  = (bi == 0) ? 1.0f : (MIND_ + softplus_(udm1));
    const float d_k1 = MIND_ + softplus_(ud0);

    const float delta = in_h / in_w;
    const float theta = (xc - in_cw) / in_w;
    const float omt   = 1.0f - theta;
    const float t1m   = theta * omt;
    const float num   = in_h * (delta * theta * theta + d_k * t1m);
    const float den   = delta + (d_k + d_k1 - 2.0f * delta) * t1m;
    const float y     = in_ch + num / den;
    const float dnum  = delta * delta * (d_k1 * theta * theta + 2.0f * delta * t1m + d_k * omt * omt);
    const float lad   = __logf(dnum) - 2.0f * __logf(den);

    const bool inside = (xr >= -TB_) && (xr <= TB_);
    y_out   = inside ? y   : xr;
    lad_out = inside ? lad : 0.0f;
}

__global__ __launch_bounds__(256) void transpose_k(const float* __restrict__ Wb,
                                                   const float* __restrict__ Wo,
                                                   float* __restrict__ wt) {
    const int t = blockIdx.x * 256 + threadIdx.x;
    if (t < WT_BLK_ELEMS) {
        const int l = t >> 12, k = (t >> 6) & 63, o = t & 63;
        wt[t] = Wb[l * 4096 + o * 64 + k];                    // WT[l][k][o]
    } else if (t < WT_BLK_ELEMS + WT_OUT_ELEMS) {
        const int t2 = t - WT_BLK_ELEMS;
        const int ih = t2 / 2560;              // i*2 + half
        const int r  = t2 - ih * 2560;
        const int k  = r / 40;
        const int c  = r - k * 40;
        const int i  = ih >> 1, half = ih & 1;
        wt[t] = (c < 37) ? Wo[(i * 74 + half * 37 + c) * 64 + k] : 0.0f;
    }
}

// Async stage NC 1024B-chunks global -> LDS; the block's WAVES_ waves split them.
template <int NC>
__device__ __forceinline__ void stage_(const float* __restrict__ g, float* lds,
                                       int wave, int wl) {
#pragma unroll
    for (int c = 0; c < (NC + WAVES_ - 1) / WAVES_; ++c) {
        const int cc = wave + WAVES_ * c;
        if (cc < NC) {
            __builtin_amdgcn_global_load_lds(
                (const __attribute__((address_space(1))) void*)(g + cc * 256 + wl * 4),
                (__attribute__((address_space(3))) void*)(lds + cc * 256), 16, 0, 0);
        }
    }
}

// acc[pi][oi] += A[p][k] * W[k][o] over k=0..63 (A-slab already relu'd if needed)
__device__ __forceinline__ void dense64_(const float* AsW, const float* Ws,
                                         int pr2, int oc, float (&acc)[8][8]) {
#pragma unroll 2
    for (int k = 0; k < 64; ++k) {
        const int key = (k >> 3) & 7;
        const float4 a0 = *(const float4*)&AsW[k * AP_ + ((pr2    ) ^ key) * 4];
        const float4 a1 = *(const float4*)&AsW[k * AP_ + ((pr2 + 1) ^ key) * 4];
        const float4 w0 = *(const float4*)&Ws[k * 64 + oc * 8];
        const float4 w1 = *(const float4*)&Ws[k * 64 + oc * 8 + 4];
        const float av[8] = {a0.x, a0.y, a0.z, a0.w, a1.x, a1.y, a1.z, a1.w};
        const float wv[8] = {w0.x, w0.y, w0.z, w0.w, w1.x, w1.y, w1.z, w1.w};
#pragma unroll
        for (int pi = 0; pi < 8; ++pi)
#pragma unroll
            for (int oi = 0; oi < 8; ++oi)
                acc[pi][oi] = fmaf(av[pi], wv[oi], acc[pi][oi]);
    }
}

// head half: acc[pi][m] over cols {oc*4+m (m<4), 32+oc}; raw A operand
__device__ __forceinline__ void head40_(const float* AsW, const float* Ws,
                                        int pr2, int oc, float (&acc)[8][5]) {
#pragma unroll 2
    for (int k = 0; k < 64; ++k) {
        const int key = (k >> 3) & 7;
        const float4 a0 = *(const float4*)&AsW[k * AP_ + ((pr2    ) ^ key) * 4];
        const float4 a1 = *(const float4*)&AsW[k * AP_ + ((pr2 + 1) ^ key) * 4];
        const float av[8] = {a0.x, a0.y, a0.z, a0.w, a1.x, a1.y, a1.z, a1.w};
        const float4 wq = *(const float4*)&Ws[k * 40 + oc * 4];   // 16B-aligned
        const float  w4 = Ws[k * 40 + 32 + oc];                   // broadcast-ish
        const float wv[5] = {wq.x, wq.y, wq.z, wq.w, w4};
#pragma unroll
        for (int pi = 0; pi < 8; ++pi)
#pragma unroll
            for (int m = 0; m < 5; ++m)
                acc[pi][m] = fmaf(av[pi], wv[m], acc[pi][m]);
    }
}

// write 8x8 tile to swizzled A-slab (optionally relu'd on the way out)
template <bool RELU>
__device__ __forceinline__ void writeA_(float* AsW, int pr2, int oc,
                                        const float (&v)[8][8]) {
#pragma unroll
    for (int oi = 0; oi < 8; ++oi) {
        float4 u0, u1;
        if (RELU) {
            u0 = {fmaxf(v[0][oi], 0.f), fmaxf(v[1][oi], 0.f),
                  fmaxf(v[2][oi], 0.f), fmaxf(v[3][oi], 0.f)};
            u1 = {fmaxf(v[4][oi], 0.f), fmaxf(v[5][oi], 0.f),
                  fmaxf(v[6][oi], 0.f), fmaxf(v[7][oi], 0.f)};
        } else {
            u0 = {v[0][oi], v[1][oi], v[2][oi], v[3][oi]};
            u1 = {v[4][oi], v[5][oi], v[6][oi], v[7][oi]};
        }
        *(float4*)&AsW[(oc * 8 + oi) * AP_ + ((pr2    ) ^ oc) * 4] = u0;
        *(float4*)&AsW[(oc * 8 + oi) * AP_ + ((pr2 + 1) ^ oc) * 4] = u1;
    }
}

__device__ __forceinline__ void load8_(const float* p, float (&d)[8]) {
    const float4 a = *(const float4*)p;
    const float4 b = *(const float4*)(p + 4);
    d[0] = a.x; d[1] = a.y; d[2] = a.z; d[3] = a.w;
    d[4] = b.x; d[5] = b.y; d[6] = b.z; d[7] = b.w;
}

__global__ __launch_bounds__(256, 2) void nsf_kernel(
    const float* __restrict__ x,
    const float* __restrict__ W_in,  const float* __restrict__ b_in,
    const float* __restrict__ b_blk, const float* __restrict__ b_out,
    const float* __restrict__ wt,
    float* __restrict__ out, int n)
{
    // 4 x 16 KB per-wave A-slabs + 16 KB shared weight tile = 80 KB exactly
    __shared__ __align__(16) float As2[WAVES_ * ASZ_];
    __shared__ __align__(16) float Ws[4096];

    const int l    = threadIdx.x;
    const int wave = l >> 6;
    const int wl   = l & 63;
    const int pr   = wl >> 3, oc = wl & 7, pr2 = pr * 2;
    float* AsW = As2 + wave * ASZ_;

    const int gidx = blockIdx.x * (WAVES_ * 64) + l;
    const int idx  = gidx < n ? gidx : (n - 1);

    float z0 = x[3 * idx + 0];
    float z1 = x[3 * idx + 1];
    float z2 = x[3 * idx + 2];
    float lad_total = 0.0f;

    stage_<16>(wt, Ws, wave, wl);   // transform 0, dense tile A0

    float H[8][8], A[8][8];         // ping-pong h / accumulator arrays

#pragma unroll 1
    for (int i = 0; i < NT_; ++i) {
        const float ident = z2;
        const float tr0   = z1;
        const float tr1   = z0;

        // ---- h-init -> H regs; slab := relu(H) ----
        {
            float idp[8], wic[8], bic[8];
#pragma unroll
            for (int t = 0; t < 8; ++t) idp[t] = __shfl(ident, pr * 8 + t, 64);
            load8_(W_in + i * 64 + oc * 8, wic);
            load8_(b_in + i * 64 + oc * 8, bic);
#pragma unroll
            for (int pi = 0; pi < 8; ++pi)
#pragma unroll
                for (int oi = 0; oi < 8; ++oi)
                    H[pi][oi] = fmaf(idp[pi], wic[oi], bic[oi]);
            writeA_<true>(AsW, pr2, oc, H);
        }

        // ======== residual half-block 1 (tiles LA, LA+1): h H -> A ========
        {
            const int LA = i * 4;
            float bac[8], bbc[8];
            load8_(b_blk + LA * 64 + oc * 8, bac);
            load8_(b_blk + (LA + 1) * 64 + oc * 8, bbc);

            __syncthreads();                        // tile A0 ready
#pragma unroll
            for (int pi = 0; pi < 8; ++pi)
#pragma unroll
                for (int oi = 0; oi < 8; ++oi) A[pi][oi] = bac[oi];
            dense64_(AsW, Ws, pr2, oc, A);          // A = t1
            __syncthreads();                        // tile consumed
            stage_<16>(wt + (size_t)(LA + 1) * 4096, Ws, wave, wl);
            writeA_<true>(AsW, pr2, oc, A);         // slab := relu(t1)
#pragma unroll
            for (int pi = 0; pi < 8; ++pi)
#pragma unroll
                for (int oi = 0; oi < 8; ++oi) A[pi][oi] = H[pi][oi] + bbc[oi];
            __syncthreads();                        // tile B0 ready
            dense64_(AsW, Ws, pr2, oc, A);          // A = h_new
            __syncthreads();                        // tile consumed
            stage_<16>(wt + (size_t)(LA + 2) * 4096, Ws, wave, wl);
            writeA_<true>(AsW, pr2, oc, A);         // slab := relu(h_new)
        }

        // ======== residual half-block 2 (tiles LA+2, LA+3): h A -> H ========
        {
            const int LA = i * 4 + 2;
            float bac[8], bbc[8];
            load8_(b_blk + LA * 64 + oc * 8, bac);
            load8_(b_blk + (LA + 1) * 64 + oc * 8, bbc);

            __syncthreads();                        // tile A1 ready
#pragma unroll
            for (int pi = 0; pi < 8; ++pi)
#pragma unroll
                for (int oi = 0; oi < 8; ++oi) H[pi][oi] = bac[oi];
            dense64_(AsW, Ws, pr2, oc, H);          // H = t1
            __syncthreads();                        // tile consumed
            stage_<16>(wt + (size_t)(LA + 1) * 4096, Ws, wave, wl);
            writeA_<true>(AsW, pr2, oc, H);         // slab := relu(t1)
#pragma unroll
            for (int pi = 0; pi < 8; ++pi)
#pragma unroll
                for (int oi = 0; oi < 8; ++oi) H[pi][oi] = A[pi][oi] + bbc[oi];
            __syncthreads();                        // tile B1 ready
            dense64_(AsW, Ws, pr2, oc, H);          // H = h_final
            __syncthreads();                        // tile consumed
            stage_<10>(wt + WT_BLK_ELEMS + (size_t)(i * 2) * 2560, Ws, wave, wl);
            writeA_<false>(AsW, pr2, oc, H);        // slab := RAW h (head input)
        }

        // ---- output head: two 40-wide halves, raw h operand ----
        float acc30[8][5] = {};
        float acc31[8][5] = {};
        __syncthreads();                           // head half-0 tile ready
        head40_(AsW, Ws, pr2, oc, acc30);
        __syncthreads();
        stage_<10>(wt + WT_BLK_ELEMS + (size_t)(i * 2 + 1) * 2560, Ws, wave, wl);
        __syncthreads();                           // head half-1 tile ready
        head40_(AsW, Ws, pr2, oc, acc31);
        __syncthreads();                           // Ws free for next transform

        if (i < NT_ - 1) stage_<16>(wt + (size_t)((i + 1) * 4) * 4096, Ws, wave, wl);

        // ---- params via per-wave slab (A-slab reused), then splines ----
        // lane cols: q = oc*4+m (m<4, always <37) and q = 32+oc (oc<5)
        const float* bo = b_out + i * 74;
        float y0, l0v, y1, l1v;
        {
#pragma unroll
            for (int pi = 0; pi < 8; ++pi) {
#pragma unroll
                for (int m = 0; m < 4; ++m)
                    AsW[(pr * 8 + pi) * PPP_ + oc * 4 + m] = acc30[pi][m];
                if (oc < 5) AsW[(pr * 8 + pi) * PPP_ + 32 + oc] = acc30[pi][4];
            }
            float p0[37];
#pragma unroll
            for (int q = 0; q < 37; ++q) p0[q] = AsW[wl * PPP_ + q] + bo[q];
            rq_spline_reg(p0, tr0, y0, l0v);
        }
        {
#pragma unroll
            for (int pi = 0; pi < 8; ++pi) {
#pragma unroll
                for (int m = 0; m < 4; ++m)
                    AsW[(pr * 8 + pi) * PPP_ + oc * 4 + m] = acc31[pi][m];
                if (oc < 5) AsW[(pr * 8 + pi) * PPP_ + 32 + oc] = acc31[pi][4];
            }
            float p1[37];
#pragma unroll
            for (int q = 0; q < 37; ++q) p1[q] = AsW[wl * PPP_ + q] + bo[37 + q];
            rq_spline_reg(p1, tr1, y1, l1v);
        }

        lad_total += l0v + l1v;
        z0 = ident;
        z1 = y0;
        z2 = y1;
    }

    if (gidx < n)
        out[gidx] = -0.5f * (z0 * z0 + z1 * z1 + z2 * z2) + LOGZ_ + lad_total;
}

}  // namespace

extern "C" void kernel_launch(void* const* d_in, const int* in_sizes, int n_in,
                              void* d_out, int out_size, void* d_ws, size_t ws_size,
                              hipStream_t stream) {
    const float* x     = (const float*)d_in[0];
    const float* W_in  = (const float*)d_in[1];
    const float* b_in  = (const float*)d_in[2];
    const float* W_blk = (const float*)d_in[3];
    const float* b_blk = (const float*)d_in[4];
    const float* W_out = (const float*)d_in[5];
    const float* b_out = (const float*)d_in[6];
    float* out = (float*)d_out;
    float* wt  = (float*)d_ws;   // 688 KB needed

    const int tot = WT_BLK_ELEMS + WT_OUT_ELEMS;   // 172032
    transpose_k<<<(tot + 255) / 256, 256, 0, stream>>>(W_blk, W_out, wt);

    const int n = in_sizes[0] / 3;
    const int grid = (n + 255) / 256;
    nsf_kernel<<<grid, 256, 0, stream>>>(x, W_in, b_in, b_blk, b_out,
                                         wt, out, n);
}